// Round 10
// baseline (264.200 us; speedup 1.0000x reference)
//
#include <hip/hip_runtime.h>

typedef unsigned int u32;
typedef unsigned long long u64;
typedef unsigned short u16;
typedef float f32x2 __attribute__((ext_vector_type(2)));

#define NB 4
#define NQ 8192
#define MARGIN 0.0625f   // >> worst-case f32 key/box rounding (~6e-3 at |coord|<=45)
#define NBKT 4096        // counting-sort buckets = top 12 Morton bits

// ---------------- workspace layout (new path) ----------------
#define OFF_C0   0u
#define OFF_C1   524288u
#define OFF_C2   786432u
#define OFF_CMP  917504u          // mask cands as CP pairs: NB*2048*32 = 262144
#define OFF_SKEY 1179648u         // u64 (morton30<<32|idx): 106496 * 8
#define OFF_BOX  2031616u         // 1152 groups * 8 f32
#define OFF_WV   2068480u         // folded w_cls @ w_fc: 96 f32
#define WS_NEW2  2068992u
// old fallback path layout:
#define OFF_CM   917504u
#define WS_OLD   (512u*1024 + 256u*1024 + 128u*1024 + 512u*1024)

struct __align__(32) CP { f32x2 x, y, z, w; };  // 2 candidates, SoA-paired
struct DM { double x, y, z, w; };               // (old path only)

__device__ __forceinline__ f32x2 fma2(f32x2 a, f32x2 b, f32x2 c) {
  return __builtin_elementwise_fma(a, b, c);    // v_pk_fma_f32 on gfx950
}

// lexicographic (d, idx) insert into sorted triple; ties -> lower index
__device__ __forceinline__ void lexins(double& e0d, double& e1d, double& e2d,
                                       int& e0i, int& e1i, int& e2i,
                                       double d, int i) {
  if (d < e2d || (d == e2d && i < e2i)) {
    if (d < e0d || (d == e0d && i < e0i)) {
      e2d = e1d; e2i = e1i; e1d = e0d; e1i = e0i; e0d = d; e0i = i;
    } else if (d < e1d || (d == e1d && i < e1i)) {
      e2d = e1d; e2i = e1i; e1d = d; e1i = i;
    } else {
      e2d = d; e2i = i;
    }
  }
}

// guarded 4-deep unpacked insert; strict < keeps incumbent (earlier-scanned)
__device__ __forceinline__ void ins4(float kv, u32 idx,
                                     float& k0, float& k1, float& k2, float& k3,
                                     u32& i0, u32& i1, u32& i2, u32& i3) {
  if (kv < k3) {
    bool lt0 = kv < k0, lt1 = kv < k1, lt2 = kv < k2;
    k3 = lt2 ? k2 : kv;               i3 = lt2 ? i2 : idx;
    k2 = lt2 ? (lt1 ? k1 : kv) : k2;  i2 = lt2 ? (lt1 ? i1 : idx) : i2;
    k1 = lt1 ? (lt0 ? k0 : kv) : k1;  i1 = lt1 ? (lt0 ? i0 : idx) : i1;
    k0 = lt0 ? kv : k0;               i0 = lt0 ? idx : i0;
  }
}

// ---------------- Morton helpers ----------------
__device__ __forceinline__ u32 spread10(u32 v) {
  v &= 0x3FFu;
  v = (v | (v << 16)) & 0x030000FFu;
  v = (v | (v << 8))  & 0x0300F00Fu;
  v = (v | (v << 4))  & 0x030C30C3u;
  v = (v | (v << 2))  & 0x09249249u;
  return v;
}
__device__ __forceinline__ u32 morton30(float x, float y, float z) {
  int xi = (int)((x + 64.f) * 8.f);
  int yi = (int)((y + 64.f) * 8.f);
  int zi = (int)((z + 64.f) * 8.f);
  xi = min(max(xi, 0), 1023); yi = min(max(yi, 0), 1023); zi = min(max(zi, 0), 1023);
  return spread10((u32)xi) | (spread10((u32)yi) << 1) | (spread10((u32)zi) << 2);
}

__device__ __forceinline__ size_t skey_abase(int arr) {
  return (arr == 0) ? 0 : (arr == 1) ? 32768 : (arr == 2) ? 49152
        : (arr == 3) ? 57344 : 73728;
}

// ---------------- pass 1: coarse counting sort -> skey ----------------
__global__ __launch_bounds__(1024) void prep_csort(
    const float* __restrict__ k2p, const float* __restrict__ k3p,
    const float* __restrict__ k4p, const float* __restrict__ mmp,
    const float* __restrict__ pts, u64* __restrict__ skey) {
  __shared__ u32 hist[NBKT];
  __shared__ u32 wsum[16];
  const int arr = blockIdx.x, b = blockIdx.y, tid = threadIdx.x;
  const int lane = tid & 63, wv = tid >> 6;
  const float* src = (arr == 0) ? k2p : (arr == 1) ? k3p : (arr == 2) ? k4p
                      : (arr == 3) ? mmp : pts;
  const int n = (arr == 0) ? 8192 : (arr == 1) ? 4096 : (arr == 2) ? 2048
                 : (arr == 3) ? 4096 : 8192;
  const float* sb = src + (size_t)b * n * 3;
  u64* skb = skey + skey_abase(arr) + (size_t)b * n;

  for (int i = tid; i < NBKT; i += 1024) hist[i] = 0;
  __syncthreads();
  for (int i = tid; i < n; i += 1024) {
    u32 k = morton30(sb[3 * i], sb[3 * i + 1], sb[3 * i + 2]);
    atomicAdd(&hist[k >> 18], 1u);
  }
  __syncthreads();
  u32 h0 = hist[4 * tid], h1 = hist[4 * tid + 1];
  u32 h2 = hist[4 * tid + 2], h3 = hist[4 * tid + 3];
  u32 s4 = h0 + h1 + h2 + h3;
  u32 inc = s4;
#pragma unroll
  for (int o = 1; o < 64; o <<= 1) {
    u32 t = __shfl_up(inc, o);
    if (lane >= o) inc += t;
  }
  if (lane == 63) wsum[wv] = inc;
  __syncthreads();
  if (tid < 16) {
    u32 v = wsum[tid], in = v;
#pragma unroll
    for (int o = 1; o < 16; o <<= 1) {
      u32 t = __shfl_up(in, o);
      if (tid >= o) in += t;
    }
    wsum[tid] = in - v;
  }
  __syncthreads();
  u32 excl = wsum[wv] + (inc - s4);
  hist[4 * tid]     = excl;
  hist[4 * tid + 1] = excl + h0;
  hist[4 * tid + 2] = excl + h0 + h1;
  hist[4 * tid + 3] = excl + h0 + h1 + h2;
  __syncthreads();
  for (int i = tid; i < n; i += 1024) {
    u32 k = morton30(sb[3 * i], sb[3 * i + 1], sb[3 * i + 2]);
    u32 pos = atomicAdd(&hist[k >> 18], 1u);
    skb[pos] = ((u64)k << 32) | (u32)i;
  }
}

// ---------------- pass 2: 512-window bitonic refine + emit ----------------
// widx 52: fold w_cls @ w_fc once into ws (hoisted out of fused phase 1).
__global__ __launch_bounds__(512) void refine_emit(
    const float* __restrict__ k2p, const float* __restrict__ k3p,
    const float* __restrict__ k4p, const float* __restrict__ mmp,
    const float* __restrict__ pts, u64* __restrict__ skey,
    CP* __restrict__ c0, CP* __restrict__ c1, CP* __restrict__ c2,
    CP* __restrict__ cmp, float* __restrict__ boxes,
    const float* __restrict__ wfc, const float* __restrict__ wcls,
    float* __restrict__ wvg) {
  const int widx = blockIdx.x, b = blockIdx.y, tid = threadIdx.x;
  if (widx == 52) {
    if (b == 0 && tid < 96) {
      float acc = 0.f;
      for (int j = 0; j < 64; ++j) acc += wcls[j] * wfc[j * 96 + tid];
      wvg[tid] = acc;
    }
    return;
  }
  __shared__ u64 ex[512];
  int arr, win;
  if (widx < 16)      { arr = 0; win = widx; }
  else if (widx < 24) { arr = 1; win = widx - 16; }
  else if (widx < 28) { arr = 2; win = widx - 24; }
  else if (widx < 36) { arr = 3; win = widx - 28; }
  else                { arr = 4; win = widx - 36; }
  const float* src = (arr == 0) ? k2p : (arr == 1) ? k3p : (arr == 2) ? k4p
                      : (arr == 3) ? mmp : pts;
  const int n = (arr == 0) ? 8192 : (arr == 1) ? 4096 : (arr == 2) ? 2048
                 : (arr == 3) ? 4096 : 8192;
  u64* skb = skey + skey_abase(arr) + (size_t)b * n;
  const int e = win * 512 + tid;
  u64 v = skb[e];

  // bitonic sort of 512 (ascending by full u64 = (key30, idx))
  for (int k = 2; k <= 512; k <<= 1) {
    for (int j = k >> 1; j > 0; j >>= 1) {
      u64 w;
      if (j < 64) {
        w = __shfl_xor(v, j);
      } else {
        __syncthreads();
        ex[tid] = v;
        __syncthreads();
        w = ex[tid ^ j];
      }
      bool up = (tid & k) == 0;
      bool lower = (tid & j) == 0;
      v = (up == lower) ? (v < w ? v : w) : (v < w ? w : v);
    }
  }
  skb[e] = v;
  if (arr == 4) return;   // queries: refined order only

  u32 p = (u32)v;
  const float* sb = src + (size_t)b * n * 3;
  float x = sb[3 * p], y = sb[3 * p + 1], z = sb[3 * p + 2];
  {
    CP* dst = (arr == 0) ? c0 : (arr == 1) ? c1 : (arr == 2) ? c2 : cmp;
    float* df = (float*)(dst + (size_t)b * (n >> 1) + (e >> 1));
    int sl = e & 1;
    df[sl]     = x;
    df[2 + sl] = y;
    df[4 + sl] = z;
    df[6 + sl] = fmaf(z, z, fmaf(y, y, x * x));
  }
  // group-of-64 AABB: wave butterfly (exact f32 bounds)
  float xlo = x, xhi = x, ylo = y, yhi = y, zlo = z, zhi = z;
#pragma unroll
  for (int off = 1; off < 64; off <<= 1) {
    xlo = fminf(xlo, __shfl_xor(xlo, off)); xhi = fmaxf(xhi, __shfl_xor(xhi, off));
    ylo = fminf(ylo, __shfl_xor(ylo, off)); yhi = fmaxf(yhi, __shfl_xor(yhi, off));
    zlo = fminf(zlo, __shfl_xor(zlo, off)); zhi = fmaxf(zhi, __shfl_xor(zhi, off));
  }
  if ((tid & 63) == 0) {
    const int nG = n >> 6, g = e >> 6;
    const int boff = (arr == 0) ? 0 : (arr == 1) ? 512 : (arr == 2) ? 768 : 896;
    float* bx = boxes + ((size_t)boff + (size_t)b * nG + g) * 8;
    bx[0] = xlo; bx[1] = xhi; bx[2] = ylo; bx[3] = yhi; bx[4] = zlo; bx[5] = zhi;
    bx[6] = 0.f; bx[7] = 0.f;
  }
}

// ---------------- fused kernel (R4 machinery + balanced wave jobs) --------
__device__ __forceinline__ void scan_pairs16(
    const CP* __restrict__ cg, u32 ebase,
    f32x2 mx2, f32x2 my2, f32x2 mz2,
    float& k0, float& k1, float& k2, float& k3,
    u32& i0, u32& i1, u32& i2, u32& i3) {
#pragma unroll 4
  for (int gg = 0; gg < 16; gg += 4) {
    f32x2 key[4];
#pragma unroll
    for (int u = 0; u < 4; ++u) {
      CP c = cg[gg + u];
      key[u] = fma2(mx2, c.x, fma2(my2, c.y, fma2(mz2, c.z, c.w)));
    }
#pragma unroll
    for (int u = 0; u < 4; ++u) {
      float ka = key[u].x, kb = key[u].y;
      if (fminf(ka, kb) < k3) {
        u32 ib = ebase + (u32)((gg + u) * 2);
        ins4(ka, ib,     k0, k1, k2, k3, i0, i1, i2, i3);
        ins4(kb, ib + 1, k0, k1, k2, k3, i0, i1, i2, i3);
      }
    }
  }
}

struct Smem8 {
  float  box[2304];                 // lvl0@0,lvl1@128,lvl2@192,mask@224 (x8)
  float  qx[32], qy[32], qz[32];
  double qdx[32], qdy[32], qdz[32], qn[32];
  u32    oq[32];
  u16    di[3][32][8][4];           // sorted-space cand indices (<8192): parts
  double mmin[32][8];
  float  wv[96];
  float  wq[32][9];
  u32    iq[32][9];
  float  contrib[32][9];
  float4 stage[4][2][64];           // per-wave double-buffer (1KB group)
  u32    list[4][64];
};

__global__ __launch_bounds__(256, 4) void fused_bal(
    const float* __restrict__ pts,
    const float* __restrict__ f2, const float* __restrict__ f3,
    const float* __restrict__ f4,
    const float* __restrict__ wvg,
    const CP* __restrict__ c0, const CP* __restrict__ c1,
    const CP* __restrict__ c2, const CP* __restrict__ cmp,
    const u64* __restrict__ skey, const float* __restrict__ boxes,
    float* __restrict__ out) {
  __shared__ Smem8 s;
  const int tid = threadIdx.x;
  const int b = blockIdx.y;
  const int tile = blockIdx.x;            // 0..255 (32-query tiles)
  const int lane = tid & 63;
  const int q = tid & 31;                 // this lane's query
  const int h = (tid >> 5) & 1;           // half within wave
  const int wid = __builtin_amdgcn_readfirstlane(tid >> 6);   // 0..3

  // phase 0/1: stage boxes, queries, precomputed folded weights
  for (int i = tid; i < 2304; i += 256) {
    int src;
    if (i < 1024)      src = (b * 128) * 8 + i;
    else if (i < 1536) src = (512 + b * 64) * 8 + (i - 1024);
    else if (i < 1792) src = (768 + b * 32) * 8 + (i - 1536);
    else               src = (896 + b * 64) * 8 + (i - 1792);
    s.box[i] = boxes[src];
  }
  if (tid < 32) {
    u64 kv = skey[73728 + (size_t)b * NQ + tile * 32 + tid];
    u32 p = (u32)kv;
    const float* pb = pts + (size_t)b * NQ * 3;
    float x = pb[3 * p], y = pb[3 * p + 1], z = pb[3 * p + 2];
    s.qx[tid] = x; s.qy[tid] = y; s.qz[tid] = z; s.oq[tid] = p;
    double dx = (double)x, dy = (double)y, dz = (double)z;
    s.qdx[tid] = dx; s.qdy[tid] = dy; s.qdz[tid] = dz;
    s.qn[tid] = (dx * dx + dy * dy) + dz * dz;   // ref f64 grouping
  } else if (tid < 128) {
    s.wv[tid - 32] = wvg[tid - 32];     // folded weights precomputed in prep
  }
  __syncthreads();

  const float qx = s.qx[q], qy = s.qy[q], qz = s.qz[q];
  const float qnf = fmaf(qz, qz, fmaf(qy, qy, qx * qx));
  const float fm2x = -2.0f * qx, fm2y = -2.0f * qy, fm2z = -2.0f * qz;
  const double qdx = s.qdx[q], qdy = s.qdy[q], qdz = s.qdz[q], qn = s.qn[q];
  const f32x2 mx2 = {fm2x, fm2x}, my2 = {fm2y, fm2y}, mz2 = {fm2z, fm2z};

  // phase 2a: balanced (lvl, parity) jobs per wave; each job = seed ->
  // vote sweep -> recheck-on-pop staged scan (identical machinery to R4).
  //   w0: lvl0.p0(P2), lvl1.p0(P4)
  //   w1: lvl0.p1(P2), lvl2.p0(P4)
  //   w2: lvl1.p1, lvl1.p2, lvl2.p1      (all P4)
  //   w3: lvl1.p3, lvl2.p2, lvl2.p3      (all P4)
  {
    int jlvl[3] = {-1, -1, -1}, jpar[3] = {0, 0, 0}, jPP[3] = {2, 2, 2};
    if (wid == 0)      { jlvl[0] = 0; jpar[0] = 0; jPP[0] = 2;
                         jlvl[1] = 1; jpar[1] = 0; jPP[1] = 4; }
    else if (wid == 1) { jlvl[0] = 0; jpar[0] = 1; jPP[0] = 2;
                         jlvl[1] = 2; jpar[1] = 0; jPP[1] = 4; }
    else if (wid == 2) { jlvl[0] = 1; jpar[0] = 1; jPP[0] = 4;
                         jlvl[1] = 1; jpar[1] = 2; jPP[1] = 4;
                         jlvl[2] = 2; jpar[2] = 1; jPP[2] = 4; }
    else               { jlvl[0] = 1; jpar[0] = 3; jPP[0] = 4;
                         jlvl[1] = 2; jpar[1] = 2; jPP[1] = 4;
                         jlvl[2] = 2; jpar[2] = 3; jPP[2] = 4; }
#pragma unroll
    for (int jj = 0; jj < 3; ++jj) {
      const int lvl = jlvl[jj];
      if (lvl < 0) break;
      const int par = jpar[jj], P = jPP[jj];
      const int M = 8192 >> lvl;
      const int nG = M >> 6;
      const int lboff = (lvl == 0) ? 0 : ((lvl == 1) ? 128 : 192);
      const CP* c4 = ((lvl == 0) ? c0 : ((lvl == 1) ? c1 : c2)) + (((size_t)b * M) >> 1);
      const int home = (lvl == 0) ? (tile >> 1) : ((lvl == 1) ? (tile >> 2) : (tile >> 3));
      const int g0 = (home & ~(P - 1)) | par;

      float k0 = __builtin_inff(), k1 = k0, k2 = k0, k3 = k0;
      u32 i0 = 0, i1 = 0, i2 = 0, i3 = 0;

      // seed: parity home group (direct, uniform s_load path)
      scan_pairs16(c4 + g0 * 32 + h * 16, (u32)(g0 * 64 + h * 32),
                   mx2, my2, mz2, k0, k1, k2, k3, i0, i1, i2, i3);

      // vote sweep (LDS boxes, stale-conservative k3)
      int nl = 0;
      const int nvote = nG / P - 1;
      for (int t = 1; t <= nvote; ++t) {
        int g = (g0 + P * t) & (nG - 1);
        const float* bx = &s.box[(lboff + g) * 8];
        float dx = fmaxf(fmaxf(bx[0] - qx, qx - bx[1]), 0.f);
        float dy = fmaxf(fmaxf(bx[2] - qy, qy - bx[3]), 0.f);
        float dz = fmaxf(fmaxf(bx[4] - qz, qz - bx[5]), 0.f);
        float lb = fmaf(dx, dx, fmaf(dy, dy, dz * dz));
        if (__any(lb < qnf + k3 + MARGIN)) {
          if (lane == 0) s.list[wid][nl] = (u32)g;
          ++nl;
        }
      }

      // staged scan; re-vote each group against CURRENT k3 before staging
      auto accept = [&](int g) -> bool {
        const float* bx = &s.box[(lboff + g) * 8];
        float dx = fmaxf(fmaxf(bx[0] - qx, qx - bx[1]), 0.f);
        float dy = fmaxf(fmaxf(bx[2] - qy, qy - bx[3]), 0.f);
        float dz = fmaxf(fmaxf(bx[4] - qz, qz - bx[5]), 0.f);
        float lb = fmaf(dx, dx, fmaf(dy, dy, dz * dz));
        return __any(lb < qnf + k3 + MARGIN);
      };
      int ip = 0, cur = 0, gcur = -1;
      float4 v;
      while (ip < nl) {
        int g = (int)s.list[wid][ip++];
        if (accept(g)) { gcur = g; v = ((const float4*)(c4 + (size_t)g * 32))[lane]; break; }
      }
      while (gcur >= 0) {
        s.stage[wid][cur][lane] = v;           // per-wave buffer, no barrier
        int gn = -1;
        while (ip < nl) {
          int g = (int)s.list[wid][ip++];
          if (accept(g)) { gn = g; break; }
        }
        if (gn >= 0) v = ((const float4*)(c4 + (size_t)gn * 32))[lane];  // in flight
        const CP* sg = (const CP*)&s.stage[wid][cur][0];
        scan_pairs16(sg + h * 16, (u32)(gcur * 64 + h * 32),
                     mx2, my2, mz2, k0, k1, k2, k3, i0, i1, i2, i3);
        gcur = gn; cur ^= 1;
      }

      const int part = par * 2 + h;
      s.di[lvl][q][part][0] = (u16)i0; s.di[lvl][q][part][1] = (u16)i1;
      s.di[lvl][q][part][2] = (u16)i2; s.di[lvl][q][part][3] = (u16)i3;
    }
  }

  // phase 2b: mask sweep, f32 keys with conservative f64 gate.
  // Gate: f32 key err < 1.5e-3 => any cand with true d2 < 0.25 satisfies
  // key32+qnf < 0.252; gated cands get the exact ref-grouped f64 d2, so the
  // final (dm < 0.25) verdict is identical to the full-f64 scan.
  {
    const CP* cmb = cmp + (size_t)b * 2048;
    int gm0 = tile >> 2;
    double dmin = __builtin_inf();
    for (int t = 0; t < 16; ++t) {
      int g = (gm0 + wid + 4 * t) & 63;
      const float* bx = &s.box[(224 + g) * 8];
      float dx = fmaxf(fmaxf(bx[0] - qx, qx - bx[1]), 0.f);
      float dy = fmaxf(fmaxf(bx[2] - qy, qy - bx[3]), 0.f);
      float dz = fmaxf(fmaxf(bx[4] - qz, qz - bx[5]), 0.f);
      float lb = fmaf(dx, dx, fmaf(dy, dy, dz * dz));
      if (__any(lb < 0.26f)) {
        const CP* cg = cmb + g * 32 + h * 16;
#pragma unroll 4
        for (int p = 0; p < 16; ++p) {
          CP c = cg[p];
          f32x2 key = fma2(mx2, c.x, fma2(my2, c.y, fma2(mz2, c.z, c.w)));
          if (fminf(key.x, key.y) + qnf < 0.252f) {
            {
              double x = (double)c.x.x, y = (double)c.y.x, z = (double)c.z.x;
              double kn2 = (x * x + y * y) + z * z;         // ref grouping
              double dot = (qdx * x + qdy * y) + qdz * z;
              dmin = fmin(dmin, (qn + kn2) - 2.0 * dot);
            }
            {
              double x = (double)c.x.y, y = (double)c.y.y, z = (double)c.z.y;
              double kn2 = (x * x + y * y) + z * z;
              double dot = (qdx * x + qdy * y) + qdz * z;
              dmin = fmin(dmin, (qn + kn2) - 2.0 * dot);
            }
          }
        }
      }
    }
    s.mmin[q][wid * 2 + h] = dmin;
  }
  __syncthreads();

  // phase 3a: f64 rescore of per-level union -> weights + ORIGINAL indices;
  // threads 96..127 emit the mask. np = 4 (lvl0) / 8 (lvl1,2) parts.
  const int gqbase = b * NQ;
  if (tid < 96) {
    const int lvl = tid >> 5;
    const int qq = tid & 31;
    const int M  = 8192 >> lvl;
    const int np = (lvl == 0) ? 4 : 8;
    const CP* c4 = ((lvl == 0) ? c0 : ((lvl == 1) ? c1 : c2)) + (((size_t)b * M) >> 1);
    const u64* skl = skey + ((lvl == 0) ? 0 : (lvl == 1) ? 32768 : 49152)
                     + (size_t)b * M;
    const double tqdx = s.qdx[qq], tqdy = s.qdy[qq], tqdz = s.qdz[qq], tqn = s.qn[qq];
    double e0 = __builtin_inf(), e1 = e0, e2 = e0;
    int j0 = 0, j1 = 0, j2 = 0;
    for (int hh = 0; hh < np; ++hh) {
#pragma unroll
      for (int r = 0; r < 4; ++r) {
        int sidx = (int)s.di[lvl][qq][hh][r];
        CP cc = c4[sidx >> 1];
        bool hi = sidx & 1;
        double x = (double)(hi ? cc.x.y : cc.x.x);
        double y = (double)(hi ? cc.y.y : cc.y.x);
        double z = (double)(hi ? cc.z.y : cc.z.x);
        int orig = (int)(u32)skl[sidx];
        double kn2 = (x * x + y * y) + z * z;         // ref grouping
        double dot = (tqdx * x + tqdy * y) + tqdz * z;
        double d2 = (tqn + kn2) - 2.0 * dot;
        lexins(e0, e1, e2, j0, j1, j2, d2, orig);
      }
    }
    double d0 = fmax(e0, 0.0), d1 = fmax(e1, 0.0), d2v = fmax(e2, 0.0);
    double r0 = 1.0 / (d0 + 1e-8);
    double r1 = 1.0 / (d1 + 1e-8);
    double r2 = 1.0 / (d2v + 1e-8);
    double sum = (r0 + r1) + r2;
    s.wq[qq][lvl * 3 + 0] = (float)(r0 / sum); s.iq[qq][lvl * 3 + 0] = (u32)j0;
    s.wq[qq][lvl * 3 + 1] = (float)(r1 / sum); s.iq[qq][lvl * 3 + 1] = (u32)j1;
    s.wq[qq][lvl * 3 + 2] = (float)(r2 / sum); s.iq[qq][lvl * 3 + 2] = (u32)j2;
  } else if (tid < 128) {
    const int qq = tid - 96;
    double dm = s.mmin[qq][0];
#pragma unroll
    for (int p = 1; p < 8; ++p) dm = fmin(dm, s.mmin[qq][p]);
    out[NB * NQ + gqbase + (int)s.oq[qq]] = (dm < 0.25) ? 1.0f : 0.0f;
  }
  __syncthreads();

  // phase 3b: 288 feature-row gather-dots over all 256 threads
  for (int item = tid; item < 288; item += 256) {
    const int qq = item & 31, j = item >> 5;      // j = lvl*3 + nb
    const int lvl = j / 3;
    const float* fp = (lvl == 0) ? f2 : ((lvl == 1) ? f3 : f4);
    const int M = 8192 >> lvl;
    const float4* row = (const float4*)(fp + ((size_t)b * M + s.iq[qq][j]) * 32);
    const float* wvp = s.wv + lvl * 32;
    float acc = 0.f;
#pragma unroll
    for (int v = 0; v < 8; ++v) {
      float4 r = row[v];
      acc += wvp[4 * v] * r.x + wvp[4 * v + 1] * r.y
           + wvp[4 * v + 2] * r.z + wvp[4 * v + 3] * r.w;
    }
    s.contrib[qq][j] = s.wq[qq][j] * acc;
  }
  __syncthreads();
  if (tid < 32) {
    const float* c = s.contrib[tid];
    float l0 = (c[0] + c[1]) + c[2];
    float l1 = (c[3] + c[4]) + c[5];
    float l2 = (c[6] + c[7]) + c[8];
    out[gqbase + (int)s.oq[tid]] = (l0 + l1) + l2;
  }
}

// ======================================================================
// Fallback paths (unchanged): packed-prep brute and raw brute.
// ======================================================================
__global__ __launch_bounds__(256) void prep_kernel(
    const float* __restrict__ k2p, const float* __restrict__ k3p,
    const float* __restrict__ k4p, const float* __restrict__ mmp,
    CP* __restrict__ c0, CP* __restrict__ c1,
    CP* __restrict__ c2, DM* __restrict__ cm) {
  int r = blockIdx.y;
  int i = blockIdx.x * 256 + threadIdx.x;
  if (r < 3) {
    const float* src = (r == 0) ? k2p : ((r == 1) ? k3p : k4p);
    CP* dst = (r == 0) ? c0 : ((r == 1) ? c1 : c2);
    int pairs = (r == 0) ? NB * 4096 : ((r == 1) ? NB * 2048 : NB * 1024);
    if (i >= pairs) return;
    const float* p = src + (size_t)i * 6;
    float x0 = p[0], y0 = p[1], z0 = p[2];
    float x1 = p[3], y1 = p[4], z1 = p[5];
    CP c;
    c.x = f32x2{x0, x1}; c.y = f32x2{y0, y1}; c.z = f32x2{z0, z1};
    c.w = f32x2{fmaf(z0, z0, fmaf(y0, y0, x0 * x0)),
                fmaf(z1, z1, fmaf(y1, y1, x1 * x1))};
    dst[i] = c;
  } else {
    if (i >= NB * 4096) return;
    double x = (double)mmp[3 * i], y = (double)mmp[3 * i + 1], z = (double)mmp[3 * i + 2];
    DM d = {x, y, z, fma(z, z, fma(y, y, x * x))};
    cm[i] = d;
  }
}

template <bool PREP>
__device__ __forceinline__ void scan_nn(
    const CP* __restrict__ cp, const float* __restrict__ raw,
    int gstart, int L, float m2x, float m2y, float m2z,
    float* kk, u32* ii) {
  float k0 = __builtin_inff(), k1 = k0, k2 = k0, k3 = k0;
  u32 i0 = 0, i1 = 0, i2 = 0, i3 = 0;
  if (PREP) {
    const f32x2 mx2 = {m2x, m2x}, my2 = {m2y, m2y}, mz2 = {m2z, m2z};
    const int G = L >> 1;
#pragma unroll 2
    for (int g = 0; g < G; g += 4) {
      f32x2 key[4];
#pragma unroll
      for (int u = 0; u < 4; ++u) {
        CP c = cp[g + u];
        key[u] = fma2(mx2, c.x, fma2(my2, c.y, fma2(mz2, c.z, c.w)));
      }
#pragma unroll
      for (int u = 0; u < 4; ++u) {
        float ka = key[u].x, kb = key[u].y;
        if (fminf(ka, kb) < k3) {
          u32 ib = (u32)(gstart + 2 * (g + u));
          ins4(ka, ib,     k0, k1, k2, k3, i0, i1, i2, i3);
          ins4(kb, ib + 1, k0, k1, k2, k3, i0, i1, i2, i3);
        }
      }
    }
  } else {
    for (int j = 0; j < L; j += 8) {
      float key[8];
#pragma unroll
      for (int u = 0; u < 8; ++u) {
        const float* p = raw + (size_t)(gstart + j + u) * 3;
        float x = p[0], y = p[1], z = p[2];
        float n2 = fmaf(z, z, fmaf(y, y, x * x));
        key[u] = fmaf(m2x, x, fmaf(m2y, y, fmaf(m2z, z, n2)));
      }
#pragma unroll
      for (int u = 0; u < 8; ++u)
        ins4(key[u], (u32)(gstart + j + u), k0, k1, k2, k3, i0, i1, i2, i3);
    }
  }
  kk[0] = k0; kk[1] = k1; kk[2] = k2; kk[3] = k3;
  ii[0] = i0; ii[1] = i1; ii[2] = i2; ii[3] = i3;
}

template <bool PREP>
__device__ __forceinline__ double scan_mask(
    const DM* __restrict__ c8, const float* __restrict__ raw,
    int gstart, int L, double m2x, double m2y, double m2z) {
  double smin = __builtin_inf();
  if (PREP) {
    for (int j = 0; j < L; j += 8) {
      double sv[8];
#pragma unroll
      for (int u = 0; u < 8; ++u) {
        DM c = c8[gstart + j + u];
        sv[u] = fma(m2x, c.x, fma(m2y, c.y, fma(m2z, c.z, c.w)));
      }
      double m01 = fmin(sv[0], sv[1]), m23 = fmin(sv[2], sv[3]);
      double m45 = fmin(sv[4], sv[5]), m67 = fmin(sv[6], sv[7]);
      smin = fmin(smin, fmin(fmin(m01, m23), fmin(m45, m67)));
    }
  } else {
    for (int j = 0; j < L; j += 4) {
#pragma unroll
      for (int u = 0; u < 4; ++u) {
        const float* p = raw + (size_t)(gstart + j + u) * 3;
        double x = (double)p[0], y = (double)p[1], z = (double)p[2];
        double kn = fma(z, z, fma(y, y, x * x));
        smin = fmin(smin, fma(m2x, x, fma(m2y, y, fma(m2z, z, kn))));
      }
    }
  }
  return smin;
}

struct Smem {
  float  qx[64], qy[64], qz[64];
  double qdx[64], qdy[64], qdz[64], qn[64];
  float  dk[3][64][4][4];
  u32    di[3][64][4][4];
  double mmin[64][8];
  float  wv[96];
  float  part[64][3];
};

template <bool PREP>
__global__ __launch_bounds__(512, 2) void fused_kernel(
    const float* __restrict__ pts,
    const float* __restrict__ k2p, const float* __restrict__ f2,
    const float* __restrict__ k3p, const float* __restrict__ f3,
    const float* __restrict__ k4p, const float* __restrict__ f4,
    const float* __restrict__ mmp,
    const float* __restrict__ wfc, const float* __restrict__ wcls,
    const CP* __restrict__ c0, const CP* __restrict__ c1,
    const CP* __restrict__ c2, const DM* __restrict__ cm,
    float* __restrict__ out) {
  __shared__ Smem s;
  const int tid = threadIdx.x;
  const int b = blockIdx.y;
  const int q0 = blockIdx.x * 64;
  const int qloc = tid & 63;
  const int wid = __builtin_amdgcn_readfirstlane(tid >> 6);

  if (tid < 64) {
    int gq = b * NQ + q0 + tid;
    float x = pts[3 * gq], y = pts[3 * gq + 1], z = pts[3 * gq + 2];
    s.qx[tid] = x; s.qy[tid] = y; s.qz[tid] = z;
    double dx = (double)x, dy = (double)y, dz = (double)z;
    s.qdx[tid] = dx; s.qdy[tid] = dy; s.qdz[tid] = dz;
    s.qn[tid] = (dx * dx + dy * dy) + dz * dz;
  } else if (tid < 160) {
    int t = tid - 64;
    float acc = 0.f;
    for (int j = 0; j < 64; ++j) acc += wcls[j] * wfc[j * 96 + t];
    s.wv[t] = acc;
  }
  __syncthreads();

  const float fm2x = -2.0f * s.qx[qloc];
  const float fm2y = -2.0f * s.qy[qloc];
  const float fm2z = -2.0f * s.qz[qloc];
  const double dm2x = -2.0 * s.qdx[qloc];
  const double dm2y = -2.0 * s.qdy[qloc];
  const double dm2z = -2.0 * s.qdz[qloc];

  {
    int lvl, prt, gstart, glen;
    if (wid < 4)      { lvl = 0; prt = wid;     gstart = wid * 2048;       glen = 2048; }
    else if (wid < 6) { lvl = 1; prt = wid - 4; gstart = (wid - 4) * 2048; glen = 2048; }
    else              { lvl = 2; prt = wid - 6; gstart = (wid - 6) * 1024; glen = 1024; }
    const CP* c4 = (lvl == 0) ? c0 : ((lvl == 1) ? c1 : c2);
    const float* raw = (lvl == 0) ? k2p : ((lvl == 1) ? k3p : k4p);
    const int      M = (lvl == 0) ? 8192 : ((lvl == 1) ? 4096 : 2048);
    float kk[4]; u32 ii[4];
    scan_nn<PREP>(c4 + (PREP ? (((size_t)b * M + gstart) >> 1) : 0),
                  raw + (size_t)b * M * 3,
                  gstart, glen, fm2x, fm2y, fm2z, kk, ii);
#pragma unroll
    for (int r = 0; r < 4; ++r) {
      s.dk[lvl][qloc][prt][r] = kk[r];
      s.di[lvl][qloc][prt][r] = ii[r];
    }
    int mstart, mlen;
    if (wid < 6) { mstart = wid * 256; mlen = 256; }
    else         { mstart = 1536 + (wid - 6) * 1280; mlen = 1280; }
    s.mmin[qloc][wid] = scan_mask<PREP>(cm + (PREP ? (size_t)b * 4096 : 0),
                                        mmp + (size_t)b * 4096 * 3,
                                        mstart, mlen, dm2x, dm2y, dm2z);
  }
  __syncthreads();

  const int gqbase = b * NQ + q0;
  if (tid < 192) {
    const int lvl = __builtin_amdgcn_readfirstlane(tid >> 6);
    const int q = tid & 63;
    const float* kp = (lvl == 0) ? k2p : ((lvl == 1) ? k3p : k4p);
    const int    M  = (lvl == 0) ? 8192 : ((lvl == 1) ? 4096 : 2048);
    const int    np = (lvl == 0) ? 4 : 2;
    const double qdx = s.qdx[q], qdy = s.qdy[q], qdz = s.qdz[q], qn = s.qn[q];
    double e0 = __builtin_inf(), e1 = e0, e2 = e0;
    int i0 = 0, i1 = 0, i2 = 0;
    for (int h = 0; h < np; ++h) {
#pragma unroll
      for (int r = 0; r < 4; ++r) {
        int idx = (int)s.di[lvl][q][h][r];
        const float* c = kp + ((size_t)b * M + idx) * 3;
        double x = (double)c[0], y = (double)c[1], z = (double)c[2];
        double kn2 = (x * x + y * y) + z * z;
        double dot = (qdx * x + qdy * y) + qdz * z;
        double d2 = (qn + kn2) - 2.0 * dot;
        lexins(e0, e1, e2, i0, i1, i2, d2, idx);
      }
    }
    double d0 = fmax(e0, 0.0), d1 = fmax(e1, 0.0), d2v = fmax(e2, 0.0);
    double r0 = 1.0 / (d0 + 1e-8);
    double r1 = 1.0 / (d1 + 1e-8);
    double r2 = 1.0 / (d2v + 1e-8);
    double sum = (r0 + r1) + r2;
    float wa = (float)(r0 / sum), wb = (float)(r1 / sum), wc = (float)(r2 / sum);
    const float* fp = (lvl == 0) ? f2 : ((lvl == 1) ? f3 : f4);
    const float* g0 = fp + ((size_t)b * M + i0) * 32;
    const float* g1 = fp + ((size_t)b * M + i1) * 32;
    const float* g2 = fp + ((size_t)b * M + i2) * 32;
    float acc = 0.f;
#pragma unroll
    for (int wd = 0; wd < 32; ++wd) {
      float v = (wa * g0[wd] + wb * g1[wd]) + wc * g2[wd];
      acc += s.wv[lvl * 32 + wd] * v;
    }
    s.part[q][lvl] = acc;
  } else if (tid < 256) {
    const int q = tid - 192;
    double sm = s.mmin[q][0];
#pragma unroll
    for (int p = 1; p < 8; ++p) sm = fmin(sm, s.mmin[q][p]);
    double dm = s.qn[q] + sm;
    out[NB * NQ + gqbase + q] = (dm < 0.25) ? 1.0f : 0.0f;
  }
  __syncthreads();
  if (tid < 64) {
    float pred = (s.part[tid][0] + s.part[tid][1]) + s.part[tid][2];
    out[gqbase + tid] = pred;
  }
}

extern "C" void kernel_launch(void* const* d_in, const int* in_sizes, int n_in,
                              void* d_out, int out_size, void* d_ws, size_t ws_size,
                              hipStream_t stream) {
  const float* pts    = (const float*)d_in[0];
  const float* known2 = (const float*)d_in[1];
  const float* feats2 = (const float*)d_in[2];
  const float* known3 = (const float*)d_in[3];
  const float* feats3 = (const float*)d_in[4];
  const float* known4 = (const float*)d_in[5];
  const float* feats4 = (const float*)d_in[6];
  const float* match  = (const float*)d_in[7];
  const float* wfc    = (const float*)d_in[8];
  const float* wcls   = (const float*)d_in[9];

  char* ws = (char*)d_ws;
  CP* c0 = (CP*)(ws + OFF_C0);
  CP* c1 = (CP*)(ws + OFF_C1);
  CP* c2 = (CP*)(ws + OFF_C2);

  if (ws_size >= WS_NEW2) {
    CP* cmp = (CP*)(ws + OFF_CMP);
    u64* skey = (u64*)(ws + OFF_SKEY);
    float* boxes = (float*)(ws + OFF_BOX);
    float* wvg = (float*)(ws + OFF_WV);
    hipLaunchKernelGGL(prep_csort, dim3(5, NB), dim3(1024), 0, stream,
                       known2, known3, known4, match, pts, skey);
    hipLaunchKernelGGL(refine_emit, dim3(53, NB), dim3(512), 0, stream,
                       known2, known3, known4, match, pts, skey,
                       c0, c1, c2, cmp, boxes, wfc, wcls, wvg);
    hipLaunchKernelGGL(fused_bal, dim3(NQ / 32, NB), dim3(256), 0, stream,
                       pts, feats2, feats3, feats4, wvg,
                       c0, c1, c2, cmp, skey, boxes, (float*)d_out);
  } else if (ws_size >= WS_OLD) {
    DM* cm = (DM*)(ws + OFF_CM);
    hipLaunchKernelGGL(prep_kernel, dim3(64, 4), dim3(256), 0, stream,
                       known2, known3, known4, match, c0, c1, c2, cm);
    hipLaunchKernelGGL(HIP_KERNEL_NAME(fused_kernel<true>), dim3(NQ / 64, NB),
                       dim3(512), 0, stream, pts, known2, feats2, known3, feats3,
                       known4, feats4, match, wfc, wcls, c0, c1, c2, cm,
                       (float*)d_out);
  } else {
    DM* cm = (DM*)(ws + OFF_CM);
    hipLaunchKernelGGL(HIP_KERNEL_NAME(fused_kernel<false>), dim3(NQ / 64, NB),
                       dim3(512), 0, stream, pts, known2, feats2, known3, feats3,
                       known4, feats4, match, wfc, wcls, c0, c1, c2, cm,
                       (float*)d_out);
  }
}

// Round 11
// 224.440 us; speedup vs baseline: 1.1772x; 1.1772x over previous
//
#include <hip/hip_runtime.h>

typedef unsigned int u32;
typedef unsigned long long u64;
typedef float f32x2 __attribute__((ext_vector_type(2)));

#define NB 4
#define NQ 8192
#define MARGIN 0.0625f   // >> worst-case f32 key/box rounding (~6e-3 at |coord|<=45)
#define NBKT 4096        // counting-sort buckets = top 12 Morton bits

// ---------------- workspace layout (new path) ----------------
#define OFF_C0   0u
#define OFF_C1   524288u
#define OFF_C2   786432u
#define OFF_CMP  917504u          // mask cands as CP pairs: NB*2048*32 = 262144
#define OFF_SKEY 1179648u         // u64 (morton30<<32|idx): 106496 * 8
#define OFF_BOX  2031616u         // 1152 groups * 8 f32
#define OFF_WV   2068480u         // folded w_cls @ w_fc: 96 f32
#define WS_NEW2  2068992u
// old fallback path layout:
#define OFF_CM   917504u
#define WS_OLD   (512u*1024 + 256u*1024 + 128u*1024 + 512u*1024)

struct __align__(32) CP { f32x2 x, y, z, w; };  // 2 candidates, SoA-paired
struct DM { double x, y, z, w; };               // (old path only)

__device__ __forceinline__ f32x2 fma2(f32x2 a, f32x2 b, f32x2 c) {
  return __builtin_elementwise_fma(a, b, c);    // v_pk_fma_f32 on gfx950
}

// lexicographic (d, idx) insert into sorted triple; ties -> lower index
__device__ __forceinline__ void lexins(double& e0d, double& e1d, double& e2d,
                                       int& e0i, int& e1i, int& e2i,
                                       double d, int i) {
  if (d < e2d || (d == e2d && i < e2i)) {
    if (d < e0d || (d == e0d && i < e0i)) {
      e2d = e1d; e2i = e1i; e1d = e0d; e1i = e0i; e0d = d; e0i = i;
    } else if (d < e1d || (d == e1d && i < e1i)) {
      e2d = e1d; e2i = e1i; e1d = d; e1i = i;
    } else {
      e2d = d; e2i = i;
    }
  }
}

// guarded 4-deep unpacked insert; strict < keeps incumbent (earlier-scanned)
__device__ __forceinline__ void ins4(float kv, u32 idx,
                                     float& k0, float& k1, float& k2, float& k3,
                                     u32& i0, u32& i1, u32& i2, u32& i3) {
  if (kv < k3) {
    bool lt0 = kv < k0, lt1 = kv < k1, lt2 = kv < k2;
    k3 = lt2 ? k2 : kv;               i3 = lt2 ? i2 : idx;
    k2 = lt2 ? (lt1 ? k1 : kv) : k2;  i2 = lt2 ? (lt1 ? i1 : idx) : i2;
    k1 = lt1 ? (lt0 ? k0 : kv) : k1;  i1 = lt1 ? (lt0 ? i0 : idx) : i1;
    k0 = lt0 ? kv : k0;               i0 = lt0 ? idx : i0;
  }
}

// ---------------- Morton helpers ----------------
__device__ __forceinline__ u32 spread10(u32 v) {
  v &= 0x3FFu;
  v = (v | (v << 16)) & 0x030000FFu;
  v = (v | (v << 8))  & 0x0300F00Fu;
  v = (v | (v << 4))  & 0x030C30C3u;
  v = (v | (v << 2))  & 0x09249249u;
  return v;
}
__device__ __forceinline__ u32 morton30(float x, float y, float z) {
  int xi = (int)((x + 64.f) * 8.f);
  int yi = (int)((y + 64.f) * 8.f);
  int zi = (int)((z + 64.f) * 8.f);
  xi = min(max(xi, 0), 1023); yi = min(max(yi, 0), 1023); zi = min(max(zi, 0), 1023);
  return spread10((u32)xi) | (spread10((u32)yi) << 1) | (spread10((u32)zi) << 2);
}

__device__ __forceinline__ size_t skey_abase(int arr) {
  return (arr == 0) ? 0 : (arr == 1) ? 32768 : (arr == 2) ? 49152
        : (arr == 3) ? 57344 : 73728;
}

// ---------------- pass 1: coarse counting sort -> skey ----------------
// Shuffle-based 3-barrier scan (measured fine in R5-R9 preps).
__global__ __launch_bounds__(1024) void prep_csort(
    const float* __restrict__ k2p, const float* __restrict__ k3p,
    const float* __restrict__ k4p, const float* __restrict__ mmp,
    const float* __restrict__ pts, u64* __restrict__ skey) {
  __shared__ u32 hist[NBKT];
  __shared__ u32 wsum[16];
  const int arr = blockIdx.x, b = blockIdx.y, tid = threadIdx.x;
  const int lane = tid & 63, wv = tid >> 6;
  const float* src = (arr == 0) ? k2p : (arr == 1) ? k3p : (arr == 2) ? k4p
                      : (arr == 3) ? mmp : pts;
  const int n = (arr == 0) ? 8192 : (arr == 1) ? 4096 : (arr == 2) ? 2048
                 : (arr == 3) ? 4096 : 8192;
  const float* sb = src + (size_t)b * n * 3;
  u64* skb = skey + skey_abase(arr) + (size_t)b * n;

  for (int i = tid; i < NBKT; i += 1024) hist[i] = 0;
  __syncthreads();
  for (int i = tid; i < n; i += 1024) {
    u32 k = morton30(sb[3 * i], sb[3 * i + 1], sb[3 * i + 2]);
    atomicAdd(&hist[k >> 18], 1u);
  }
  __syncthreads();
  u32 h0 = hist[4 * tid], h1 = hist[4 * tid + 1];
  u32 h2 = hist[4 * tid + 2], h3 = hist[4 * tid + 3];
  u32 s4 = h0 + h1 + h2 + h3;
  u32 inc = s4;
#pragma unroll
  for (int o = 1; o < 64; o <<= 1) {
    u32 t = __shfl_up(inc, o);
    if (lane >= o) inc += t;
  }
  if (lane == 63) wsum[wv] = inc;
  __syncthreads();
  if (tid < 16) {
    u32 v = wsum[tid], in = v;
#pragma unroll
    for (int o = 1; o < 16; o <<= 1) {
      u32 t = __shfl_up(in, o);
      if (tid >= o) in += t;
    }
    wsum[tid] = in - v;
  }
  __syncthreads();
  u32 excl = wsum[wv] + (inc - s4);
  hist[4 * tid]     = excl;
  hist[4 * tid + 1] = excl + h0;
  hist[4 * tid + 2] = excl + h0 + h1;
  hist[4 * tid + 3] = excl + h0 + h1 + h2;
  __syncthreads();
  for (int i = tid; i < n; i += 1024) {
    u32 k = morton30(sb[3 * i], sb[3 * i + 1], sb[3 * i + 2]);
    u32 pos = atomicAdd(&hist[k >> 18], 1u);
    skb[pos] = ((u64)k << 32) | (u32)i;
  }
}

// ---------------- pass 2: 512-window bitonic refine + emit ----------------
// widx 52: fold w_cls @ w_fc once into ws (hoisted out of fused phase 1).
__global__ __launch_bounds__(512) void refine_emit(
    const float* __restrict__ k2p, const float* __restrict__ k3p,
    const float* __restrict__ k4p, const float* __restrict__ mmp,
    const float* __restrict__ pts, u64* __restrict__ skey,
    CP* __restrict__ c0, CP* __restrict__ c1, CP* __restrict__ c2,
    CP* __restrict__ cmp, float* __restrict__ boxes,
    const float* __restrict__ wfc, const float* __restrict__ wcls,
    float* __restrict__ wvg) {
  const int widx = blockIdx.x, b = blockIdx.y, tid = threadIdx.x;
  if (widx == 52) {
    if (b == 0 && tid < 96) {
      float acc = 0.f;
      for (int j = 0; j < 64; ++j) acc += wcls[j] * wfc[j * 96 + tid];
      wvg[tid] = acc;
    }
    return;
  }
  __shared__ u64 ex[512];
  int arr, win;
  if (widx < 16)      { arr = 0; win = widx; }
  else if (widx < 24) { arr = 1; win = widx - 16; }
  else if (widx < 28) { arr = 2; win = widx - 24; }
  else if (widx < 36) { arr = 3; win = widx - 28; }
  else                { arr = 4; win = widx - 36; }
  const float* src = (arr == 0) ? k2p : (arr == 1) ? k3p : (arr == 2) ? k4p
                      : (arr == 3) ? mmp : pts;
  const int n = (arr == 0) ? 8192 : (arr == 1) ? 4096 : (arr == 2) ? 2048
                 : (arr == 3) ? 4096 : 8192;
  u64* skb = skey + skey_abase(arr) + (size_t)b * n;
  const int e = win * 512 + tid;
  u64 v = skb[e];

  // bitonic sort of 512 (ascending by full u64 = (key30, idx))
  for (int k = 2; k <= 512; k <<= 1) {
    for (int j = k >> 1; j > 0; j >>= 1) {
      u64 w;
      if (j < 64) {
        w = __shfl_xor(v, j);
      } else {
        __syncthreads();
        ex[tid] = v;
        __syncthreads();
        w = ex[tid ^ j];
      }
      bool up = (tid & k) == 0;
      bool lower = (tid & j) == 0;
      v = (up == lower) ? (v < w ? v : w) : (v < w ? w : v);
    }
  }
  skb[e] = v;
  if (arr == 4) return;   // queries: refined order only

  u32 p = (u32)v;
  const float* sb = src + (size_t)b * n * 3;
  float x = sb[3 * p], y = sb[3 * p + 1], z = sb[3 * p + 2];
  {
    CP* dst = (arr == 0) ? c0 : (arr == 1) ? c1 : (arr == 2) ? c2 : cmp;
    float* df = (float*)(dst + (size_t)b * (n >> 1) + (e >> 1));
    int sl = e & 1;
    df[sl]     = x;
    df[2 + sl] = y;
    df[4 + sl] = z;
    df[6 + sl] = fmaf(z, z, fmaf(y, y, x * x));
  }
  // group-of-64 AABB: wave butterfly (exact f32 bounds)
  float xlo = x, xhi = x, ylo = y, yhi = y, zlo = z, zhi = z;
#pragma unroll
  for (int off = 1; off < 64; off <<= 1) {
    xlo = fminf(xlo, __shfl_xor(xlo, off)); xhi = fmaxf(xhi, __shfl_xor(xhi, off));
    ylo = fminf(ylo, __shfl_xor(ylo, off)); yhi = fmaxf(yhi, __shfl_xor(yhi, off));
    zlo = fminf(zlo, __shfl_xor(zlo, off)); zhi = fmaxf(zhi, __shfl_xor(zhi, off));
  }
  if ((tid & 63) == 0) {
    const int nG = n >> 6, g = e >> 6;
    const int boff = (arr == 0) ? 0 : (arr == 1) ? 512 : (arr == 2) ? 768 : 896;
    float* bx = boxes + ((size_t)boff + (size_t)b * nG + g) * 8;
    bx[0] = xlo; bx[1] = xhi; bx[2] = ylo; bx[3] = yhi; bx[4] = zlo; bx[5] = zhi;
    bx[6] = 0.f; bx[7] = 0.f;
  }
}

// ---------------- fused kernel (R4-measured optimum: 32-q tiles) ----------
__device__ __forceinline__ void scan_pairs16(
    const CP* __restrict__ cg, u32 ebase,
    f32x2 mx2, f32x2 my2, f32x2 mz2,
    float& k0, float& k1, float& k2, float& k3,
    u32& i0, u32& i1, u32& i2, u32& i3) {
#pragma unroll 4
  for (int gg = 0; gg < 16; gg += 4) {
    f32x2 key[4];
#pragma unroll
    for (int u = 0; u < 4; ++u) {
      CP c = cg[gg + u];
      key[u] = fma2(mx2, c.x, fma2(my2, c.y, fma2(mz2, c.z, c.w)));
    }
#pragma unroll
    for (int u = 0; u < 4; ++u) {
      float ka = key[u].x, kb = key[u].y;
      if (fminf(ka, kb) < k3) {
        u32 ib = ebase + (u32)((gg + u) * 2);
        ins4(ka, ib,     k0, k1, k2, k3, i0, i1, i2, i3);
        ins4(kb, ib + 1, k0, k1, k2, k3, i0, i1, i2, i3);
      }
    }
  }
}

struct Smem4 {
  float  box[2304];                 // lvl0@0,lvl1@128,lvl2@192,mask@224 (x8)
  float  qx[32], qy[32], qz[32];
  double qdx[32], qdy[32], qdz[32], qn[32];
  u32    oq[32];
  u32    di[3][32][4][4];
  double mmin[32][8];
  float  wv[96];
  float  wq[32][9];
  u32    iq[32][9];
  float  contrib[32][9];
  float4 stage[4][2][64];           // per-wave double-buffer (1KB group)
  u32    list[4][64];
};

__global__ __launch_bounds__(256, 4) void fused_sorted3(
    const float* __restrict__ pts,
    const float* __restrict__ f2, const float* __restrict__ f3,
    const float* __restrict__ f4,
    const float* __restrict__ wvg,
    const CP* __restrict__ c0, const CP* __restrict__ c1,
    const CP* __restrict__ c2, const CP* __restrict__ cmp,
    const u64* __restrict__ skey, const float* __restrict__ boxes,
    float* __restrict__ out) {
  __shared__ Smem4 s;
  const int tid = threadIdx.x;
  const int b = blockIdx.y;
  const int tile = blockIdx.x;            // 0..255 (32-query tiles)
  const int lane = tid & 63;
  const int q = tid & 31;                 // this lane's query
  const int h = (tid >> 5) & 1;           // half within wave
  const int wid = __builtin_amdgcn_readfirstlane(tid >> 6);   // 0..3

  // phase 0/1: stage boxes, queries, precomputed folded weights
  for (int i = tid; i < 2304; i += 256) {
    int src;
    if (i < 1024)      src = (b * 128) * 8 + i;
    else if (i < 1536) src = (512 + b * 64) * 8 + (i - 1024);
    else if (i < 1792) src = (768 + b * 32) * 8 + (i - 1536);
    else               src = (896 + b * 64) * 8 + (i - 1792);
    s.box[i] = boxes[src];
  }
  if (tid < 32) {
    u64 kv = skey[73728 + (size_t)b * NQ + tile * 32 + tid];
    u32 p = (u32)kv;
    const float* pb = pts + (size_t)b * NQ * 3;
    float x = pb[3 * p], y = pb[3 * p + 1], z = pb[3 * p + 2];
    s.qx[tid] = x; s.qy[tid] = y; s.qz[tid] = z; s.oq[tid] = p;
    double dx = (double)x, dy = (double)y, dz = (double)z;
    s.qdx[tid] = dx; s.qdy[tid] = dy; s.qdz[tid] = dz;
    s.qn[tid] = (dx * dx + dy * dy) + dz * dz;   // ref f64 grouping
  } else if (tid < 128) {
    s.wv[tid - 32] = wvg[tid - 32];     // folded weights precomputed in prep
  }
  __syncthreads();

  const float qx = s.qx[q], qy = s.qy[q], qz = s.qz[q];
  const float qnf = fmaf(qz, qz, fmaf(qy, qy, qx * qx));
  const float fm2x = -2.0f * qx, fm2y = -2.0f * qy, fm2z = -2.0f * qz;
  const double qdx = s.qdx[q], qdy = s.qdy[q], qdz = s.qdz[q], qn = s.qn[q];
  const f32x2 mx2 = {fm2x, fm2x}, my2 = {fm2y, fm2y}, mz2 = {fm2z, fm2z};

  // phase 2a: seed -> vote sweep -> staged scan with recheck-on-pop.
  // waves 0,1: lvl0 parity sets; wave 2: lvl1; wave 3: lvl2.
  // half h scans pairs [16h,16h+16) of each accepted group (no redundancy).
  {
    int lvl, part, nG, g0, stride, nvote, lboff;
    if (wid < 2)      { lvl = 0; nG = 128; stride = 2; nvote = 63;
                        g0 = (((tile * 128) >> 8) & ~1) | wid;
                        part = wid * 2 + h; lboff = 0; }
    else if (wid == 2){ lvl = 1; nG = 64;  stride = 1; nvote = 63;
                        g0 = (tile * 64) >> 8; part = h; lboff = 128; }
    else              { lvl = 2; nG = 32;  stride = 1; nvote = 31;
                        g0 = (tile * 32) >> 8; part = h; lboff = 192; }
    const int M = 8192 >> lvl;
    const CP* c4 = ((lvl == 0) ? c0 : ((lvl == 1) ? c1 : c2)) + (((size_t)b * M) >> 1);

    float k0 = __builtin_inff(), k1 = k0, k2 = k0, k3 = k0;
    u32 i0 = 0, i1 = 0, i2 = 0, i3 = 0;

    // seed: home group (direct, uniform s_load path), establishes k3
    scan_pairs16(c4 + g0 * 32 + h * 16, (u32)(g0 * 64 + h * 32),
                 mx2, my2, mz2, k0, k1, k2, k3, i0, i1, i2, i3);

    // vote sweep (LDS boxes, stale-conservative k3)
    int nl = 0;
    for (int t = 1; t <= nvote; ++t) {
      int g = (g0 + stride * t) & (nG - 1);
      const float* bx = &s.box[(lboff + g) * 8];
      float dx = fmaxf(fmaxf(bx[0] - qx, qx - bx[1]), 0.f);
      float dy = fmaxf(fmaxf(bx[2] - qy, qy - bx[3]), 0.f);
      float dz = fmaxf(fmaxf(bx[4] - qz, qz - bx[5]), 0.f);
      float lb = fmaf(dx, dx, fmaf(dy, dy, dz * dz));
      if (__any(lb < qnf + k3 + MARGIN)) {
        if (lane == 0) s.list[wid][nl] = (u32)g;
        ++nl;
      }
    }

    // staged scan; re-vote each group against CURRENT k3 before staging
    auto accept = [&](int g) -> bool {
      const float* bx = &s.box[(lboff + g) * 8];
      float dx = fmaxf(fmaxf(bx[0] - qx, qx - bx[1]), 0.f);
      float dy = fmaxf(fmaxf(bx[2] - qy, qy - bx[3]), 0.f);
      float dz = fmaxf(fmaxf(bx[4] - qz, qz - bx[5]), 0.f);
      float lb = fmaf(dx, dx, fmaf(dy, dy, dz * dz));
      return __any(lb < qnf + k3 + MARGIN);
    };
    int ip = 0, cur = 0, gcur = -1;
    float4 v;
    while (ip < nl) {
      int g = (int)s.list[wid][ip++];
      if (accept(g)) { gcur = g; v = ((const float4*)(c4 + (size_t)g * 32))[lane]; break; }
    }
    while (gcur >= 0) {
      s.stage[wid][cur][lane] = v;           // per-wave buffer, no barrier
      int gn = -1;
      while (ip < nl) {
        int g = (int)s.list[wid][ip++];
        if (accept(g)) { gn = g; break; }
      }
      if (gn >= 0) v = ((const float4*)(c4 + (size_t)gn * 32))[lane];  // in flight
      const CP* sg = (const CP*)&s.stage[wid][cur][0];
      scan_pairs16(sg + h * 16, (u32)(gcur * 64 + h * 32),
                   mx2, my2, mz2, k0, k1, k2, k3, i0, i1, i2, i3);
      gcur = gn; cur ^= 1;
    }

    s.di[lvl][q][part][0] = i0; s.di[lvl][q][part][1] = i1;
    s.di[lvl][q][part][2] = i2; s.di[lvl][q][part][3] = i3;
  }

  // phase 2b: mask sweep, f32 keys with conservative f64 gate.
  // Gate: f32 key err < 1.5e-3 => any cand with true d2 < 0.25 satisfies
  // key32+qnf < 0.252; gated cands get the exact ref-grouped f64 d2, so the
  // final (dm < 0.25) verdict is identical to the full-f64 scan.
  {
    const CP* cmb = cmp + (size_t)b * 2048;
    int gm0 = tile >> 2;
    double dmin = __builtin_inf();
    for (int t = 0; t < 16; ++t) {
      int g = (gm0 + wid + 4 * t) & 63;
      const float* bx = &s.box[(224 + g) * 8];
      float dx = fmaxf(fmaxf(bx[0] - qx, qx - bx[1]), 0.f);
      float dy = fmaxf(fmaxf(bx[2] - qy, qy - bx[3]), 0.f);
      float dz = fmaxf(fmaxf(bx[4] - qz, qz - bx[5]), 0.f);
      float lb = fmaf(dx, dx, fmaf(dy, dy, dz * dz));
      if (__any(lb < 0.26f)) {
        const CP* cg = cmb + g * 32 + h * 16;
#pragma unroll 4
        for (int p = 0; p < 16; ++p) {
          CP c = cg[p];
          f32x2 key = fma2(mx2, c.x, fma2(my2, c.y, fma2(mz2, c.z, c.w)));
          if (fminf(key.x, key.y) + qnf < 0.252f) {
            {
              double x = (double)c.x.x, y = (double)c.y.x, z = (double)c.z.x;
              double kn2 = (x * x + y * y) + z * z;         // ref grouping
              double dot = (qdx * x + qdy * y) + qdz * z;
              dmin = fmin(dmin, (qn + kn2) - 2.0 * dot);
            }
            {
              double x = (double)c.x.y, y = (double)c.y.y, z = (double)c.z.y;
              double kn2 = (x * x + y * y) + z * z;
              double dot = (qdx * x + qdy * y) + qdz * z;
              dmin = fmin(dmin, (qn + kn2) - 2.0 * dot);
            }
          }
        }
      }
    }
    s.mmin[q][wid * 2 + h] = dmin;
  }
  __syncthreads();

  // phase 3a: f64 rescore of per-level union -> weights + ORIGINAL indices;
  // threads 96..127 emit the mask.
  const int gqbase = b * NQ;
  if (tid < 96) {
    const int lvl = tid >> 5;
    const int qq = tid & 31;
    const int M  = 8192 >> lvl;
    const int np = (lvl == 0) ? 4 : 2;
    const CP* c4 = ((lvl == 0) ? c0 : ((lvl == 1) ? c1 : c2)) + (((size_t)b * M) >> 1);
    const u64* skl = skey + ((lvl == 0) ? 0 : (lvl == 1) ? 32768 : 49152)
                     + (size_t)b * M;
    const double tqdx = s.qdx[qq], tqdy = s.qdy[qq], tqdz = s.qdz[qq], tqn = s.qn[qq];
    double e0 = __builtin_inf(), e1 = e0, e2 = e0;
    int j0 = 0, j1 = 0, j2 = 0;
    for (int hh = 0; hh < np; ++hh) {
#pragma unroll
      for (int r = 0; r < 4; ++r) {
        int sidx = (int)s.di[lvl][qq][hh][r];
        CP cc = c4[sidx >> 1];
        bool hi = sidx & 1;
        double x = (double)(hi ? cc.x.y : cc.x.x);
        double y = (double)(hi ? cc.y.y : cc.y.x);
        double z = (double)(hi ? cc.z.y : cc.z.x);
        int orig = (int)(u32)skl[sidx];
        double kn2 = (x * x + y * y) + z * z;         // ref grouping
        double dot = (tqdx * x + tqdy * y) + tqdz * z;
        double d2 = (tqn + kn2) - 2.0 * dot;
        lexins(e0, e1, e2, j0, j1, j2, d2, orig);
      }
    }
    double d0 = fmax(e0, 0.0), d1 = fmax(e1, 0.0), d2v = fmax(e2, 0.0);
    double r0 = 1.0 / (d0 + 1e-8);
    double r1 = 1.0 / (d1 + 1e-8);
    double r2 = 1.0 / (d2v + 1e-8);
    double sum = (r0 + r1) + r2;
    s.wq[qq][lvl * 3 + 0] = (float)(r0 / sum); s.iq[qq][lvl * 3 + 0] = (u32)j0;
    s.wq[qq][lvl * 3 + 1] = (float)(r1 / sum); s.iq[qq][lvl * 3 + 1] = (u32)j1;
    s.wq[qq][lvl * 3 + 2] = (float)(r2 / sum); s.iq[qq][lvl * 3 + 2] = (u32)j2;
  } else if (tid < 128) {
    const int qq = tid - 96;
    double dm = s.mmin[qq][0];
#pragma unroll
    for (int p = 1; p < 8; ++p) dm = fmin(dm, s.mmin[qq][p]);
    out[NB * NQ + gqbase + (int)s.oq[qq]] = (dm < 0.25) ? 1.0f : 0.0f;
  }
  __syncthreads();

  // phase 3b: 288 feature-row gather-dots over all 256 threads
  for (int item = tid; item < 288; item += 256) {
    const int qq = item & 31, j = item >> 5;      // j = lvl*3 + nb
    const int lvl = j / 3;
    const float* fp = (lvl == 0) ? f2 : ((lvl == 1) ? f3 : f4);
    const int M = 8192 >> lvl;
    const float4* row = (const float4*)(fp + ((size_t)b * M + s.iq[qq][j]) * 32);
    const float* wvp = s.wv + lvl * 32;
    float acc = 0.f;
#pragma unroll
    for (int v = 0; v < 8; ++v) {
      float4 r = row[v];
      acc += wvp[4 * v] * r.x + wvp[4 * v + 1] * r.y
           + wvp[4 * v + 2] * r.z + wvp[4 * v + 3] * r.w;
    }
    s.contrib[qq][j] = s.wq[qq][j] * acc;
  }
  __syncthreads();
  if (tid < 32) {
    const float* c = s.contrib[tid];
    float l0 = (c[0] + c[1]) + c[2];
    float l1 = (c[3] + c[4]) + c[5];
    float l2 = (c[6] + c[7]) + c[8];
    out[gqbase + (int)s.oq[tid]] = (l0 + l1) + l2;
  }
}

// ======================================================================
// Fallback paths (unchanged): packed-prep brute and raw brute.
// ======================================================================
__global__ __launch_bounds__(256) void prep_kernel(
    const float* __restrict__ k2p, const float* __restrict__ k3p,
    const float* __restrict__ k4p, const float* __restrict__ mmp,
    CP* __restrict__ c0, CP* __restrict__ c1,
    CP* __restrict__ c2, DM* __restrict__ cm) {
  int r = blockIdx.y;
  int i = blockIdx.x * 256 + threadIdx.x;
  if (r < 3) {
    const float* src = (r == 0) ? k2p : ((r == 1) ? k3p : k4p);
    CP* dst = (r == 0) ? c0 : ((r == 1) ? c1 : c2);
    int pairs = (r == 0) ? NB * 4096 : ((r == 1) ? NB * 2048 : NB * 1024);
    if (i >= pairs) return;
    const float* p = src + (size_t)i * 6;
    float x0 = p[0], y0 = p[1], z0 = p[2];
    float x1 = p[3], y1 = p[4], z1 = p[5];
    CP c;
    c.x = f32x2{x0, x1}; c.y = f32x2{y0, y1}; c.z = f32x2{z0, z1};
    c.w = f32x2{fmaf(z0, z0, fmaf(y0, y0, x0 * x0)),
                fmaf(z1, z1, fmaf(y1, y1, x1 * x1))};
    dst[i] = c;
  } else {
    if (i >= NB * 4096) return;
    double x = (double)mmp[3 * i], y = (double)mmp[3 * i + 1], z = (double)mmp[3 * i + 2];
    DM d = {x, y, z, fma(z, z, fma(y, y, x * x))};
    cm[i] = d;
  }
}

template <bool PREP>
__device__ __forceinline__ void scan_nn(
    const CP* __restrict__ cp, const float* __restrict__ raw,
    int gstart, int L, float m2x, float m2y, float m2z,
    float* kk, u32* ii) {
  float k0 = __builtin_inff(), k1 = k0, k2 = k0, k3 = k0;
  u32 i0 = 0, i1 = 0, i2 = 0, i3 = 0;
  if (PREP) {
    const f32x2 mx2 = {m2x, m2x}, my2 = {m2y, m2y}, mz2 = {m2z, m2z};
    const int G = L >> 1;
#pragma unroll 2
    for (int g = 0; g < G; g += 4) {
      f32x2 key[4];
#pragma unroll
      for (int u = 0; u < 4; ++u) {
        CP c = cp[g + u];
        key[u] = fma2(mx2, c.x, fma2(my2, c.y, fma2(mz2, c.z, c.w)));
      }
#pragma unroll
      for (int u = 0; u < 4; ++u) {
        float ka = key[u].x, kb = key[u].y;
        if (fminf(ka, kb) < k3) {
          u32 ib = (u32)(gstart + 2 * (g + u));
          ins4(ka, ib,     k0, k1, k2, k3, i0, i1, i2, i3);
          ins4(kb, ib + 1, k0, k1, k2, k3, i0, i1, i2, i3);
        }
      }
    }
  } else {
    for (int j = 0; j < L; j += 8) {
      float key[8];
#pragma unroll
      for (int u = 0; u < 8; ++u) {
        const float* p = raw + (size_t)(gstart + j + u) * 3;
        float x = p[0], y = p[1], z = p[2];
        float n2 = fmaf(z, z, fmaf(y, y, x * x));
        key[u] = fmaf(m2x, x, fmaf(m2y, y, fmaf(m2z, z, n2)));
      }
#pragma unroll
      for (int u = 0; u < 8; ++u)
        ins4(key[u], (u32)(gstart + j + u), k0, k1, k2, k3, i0, i1, i2, i3);
    }
  }
  kk[0] = k0; kk[1] = k1; kk[2] = k2; kk[3] = k3;
  ii[0] = i0; ii[1] = i1; ii[2] = i2; ii[3] = i3;
}

template <bool PREP>
__device__ __forceinline__ double scan_mask(
    const DM* __restrict__ c8, const float* __restrict__ raw,
    int gstart, int L, double m2x, double m2y, double m2z) {
  double smin = __builtin_inf();
  if (PREP) {
    for (int j = 0; j < L; j += 8) {
      double sv[8];
#pragma unroll
      for (int u = 0; u < 8; ++u) {
        DM c = c8[gstart + j + u];
        sv[u] = fma(m2x, c.x, fma(m2y, c.y, fma(m2z, c.z, c.w)));
      }
      double m01 = fmin(sv[0], sv[1]), m23 = fmin(sv[2], sv[3]);
      double m45 = fmin(sv[4], sv[5]), m67 = fmin(sv[6], sv[7]);
      smin = fmin(smin, fmin(fmin(m01, m23), fmin(m45, m67)));
    }
  } else {
    for (int j = 0; j < L; j += 4) {
#pragma unroll
      for (int u = 0; u < 4; ++u) {
        const float* p = raw + (size_t)(gstart + j + u) * 3;
        double x = (double)p[0], y = (double)p[1], z = (double)p[2];
        double kn = fma(z, z, fma(y, y, x * x));
        smin = fmin(smin, fma(m2x, x, fma(m2y, y, fma(m2z, z, kn))));
      }
    }
  }
  return smin;
}

struct Smem {
  float  qx[64], qy[64], qz[64];
  double qdx[64], qdy[64], qdz[64], qn[64];
  float  dk[3][64][4][4];
  u32    di[3][64][4][4];
  double mmin[64][8];
  float  wv[96];
  float  part[64][3];
};

template <bool PREP>
__global__ __launch_bounds__(512, 2) void fused_kernel(
    const float* __restrict__ pts,
    const float* __restrict__ k2p, const float* __restrict__ f2,
    const float* __restrict__ k3p, const float* __restrict__ f3,
    const float* __restrict__ k4p, const float* __restrict__ f4,
    const float* __restrict__ mmp,
    const float* __restrict__ wfc, const float* __restrict__ wcls,
    const CP* __restrict__ c0, const CP* __restrict__ c1,
    const CP* __restrict__ c2, const DM* __restrict__ cm,
    float* __restrict__ out) {
  __shared__ Smem s;
  const int tid = threadIdx.x;
  const int b = blockIdx.y;
  const int q0 = blockIdx.x * 64;
  const int qloc = tid & 63;
  const int wid = __builtin_amdgcn_readfirstlane(tid >> 6);

  if (tid < 64) {
    int gq = b * NQ + q0 + tid;
    float x = pts[3 * gq], y = pts[3 * gq + 1], z = pts[3 * gq + 2];
    s.qx[tid] = x; s.qy[tid] = y; s.qz[tid] = z;
    double dx = (double)x, dy = (double)y, dz = (double)z;
    s.qdx[tid] = dx; s.qdy[tid] = dy; s.qdz[tid] = dz;
    s.qn[tid] = (dx * dx + dy * dy) + dz * dz;
  } else if (tid < 160) {
    int t = tid - 64;
    float acc = 0.f;
    for (int j = 0; j < 64; ++j) acc += wcls[j] * wfc[j * 96 + t];
    s.wv[t] = acc;
  }
  __syncthreads();

  const float fm2x = -2.0f * s.qx[qloc];
  const float fm2y = -2.0f * s.qy[qloc];
  const float fm2z = -2.0f * s.qz[qloc];
  const double dm2x = -2.0 * s.qdx[qloc];
  const double dm2y = -2.0 * s.qdy[qloc];
  const double dm2z = -2.0 * s.qdz[qloc];

  {
    int lvl, prt, gstart, glen;
    if (wid < 4)      { lvl = 0; prt = wid;     gstart = wid * 2048;       glen = 2048; }
    else if (wid < 6) { lvl = 1; prt = wid - 4; gstart = (wid - 4) * 2048; glen = 2048; }
    else              { lvl = 2; prt = wid - 6; gstart = (wid - 6) * 1024; glen = 1024; }
    const CP* c4 = (lvl == 0) ? c0 : ((lvl == 1) ? c1 : c2);
    const float* raw = (lvl == 0) ? k2p : ((lvl == 1) ? k3p : k4p);
    const int      M = (lvl == 0) ? 8192 : ((lvl == 1) ? 4096 : 2048);
    float kk[4]; u32 ii[4];
    scan_nn<PREP>(c4 + (PREP ? (((size_t)b * M + gstart) >> 1) : 0),
                  raw + (size_t)b * M * 3,
                  gstart, glen, fm2x, fm2y, fm2z, kk, ii);
#pragma unroll
    for (int r = 0; r < 4; ++r) {
      s.dk[lvl][qloc][prt][r] = kk[r];
      s.di[lvl][qloc][prt][r] = ii[r];
    }
    int mstart, mlen;
    if (wid < 6) { mstart = wid * 256; mlen = 256; }
    else         { mstart = 1536 + (wid - 6) * 1280; mlen = 1280; }
    s.mmin[qloc][wid] = scan_mask<PREP>(cm + (PREP ? (size_t)b * 4096 : 0),
                                        mmp + (size_t)b * 4096 * 3,
                                        mstart, mlen, dm2x, dm2y, dm2z);
  }
  __syncthreads();

  const int gqbase = b * NQ + q0;
  if (tid < 192) {
    const int lvl = __builtin_amdgcn_readfirstlane(tid >> 6);
    const int q = tid & 63;
    const float* kp = (lvl == 0) ? k2p : ((lvl == 1) ? k3p : k4p);
    const int    M  = (lvl == 0) ? 8192 : ((lvl == 1) ? 4096 : 2048);
    const int    np = (lvl == 0) ? 4 : 2;
    const double qdx = s.qdx[q], qdy = s.qdy[q], qdz = s.qdz[q], qn = s.qn[q];
    double e0 = __builtin_inf(), e1 = e0, e2 = e0;
    int i0 = 0, i1 = 0, i2 = 0;
    for (int h = 0; h < np; ++h) {
#pragma unroll
      for (int r = 0; r < 4; ++r) {
        int idx = (int)s.di[lvl][q][h][r];
        const float* c = kp + ((size_t)b * M + idx) * 3;
        double x = (double)c[0], y = (double)c[1], z = (double)c[2];
        double kn2 = (x * x + y * y) + z * z;
        double dot = (qdx * x + qdy * y) + qdz * z;
        double d2 = (qn + kn2) - 2.0 * dot;
        lexins(e0, e1, e2, i0, i1, i2, d2, idx);
      }
    }
    double d0 = fmax(e0, 0.0), d1 = fmax(e1, 0.0), d2v = fmax(e2, 0.0);
    double r0 = 1.0 / (d0 + 1e-8);
    double r1 = 1.0 / (d1 + 1e-8);
    double r2 = 1.0 / (d2v + 1e-8);
    double sum = (r0 + r1) + r2;
    float wa = (float)(r0 / sum), wb = (float)(r1 / sum), wc = (float)(r2 / sum);
    const float* fp = (lvl == 0) ? f2 : ((lvl == 1) ? f3 : f4);
    const float* g0 = fp + ((size_t)b * M + i0) * 32;
    const float* g1 = fp + ((size_t)b * M + i1) * 32;
    const float* g2 = fp + ((size_t)b * M + i2) * 32;
    float acc = 0.f;
#pragma unroll
    for (int wd = 0; wd < 32; ++wd) {
      float v = (wa * g0[wd] + wb * g1[wd]) + wc * g2[wd];
      acc += s.wv[lvl * 32 + wd] * v;
    }
    s.part[q][lvl] = acc;
  } else if (tid < 256) {
    const int q = tid - 192;
    double sm = s.mmin[q][0];
#pragma unroll
    for (int p = 1; p < 8; ++p) sm = fmin(sm, s.mmin[q][p]);
    double dm = s.qn[q] + sm;
    out[NB * NQ + gqbase + q] = (dm < 0.25) ? 1.0f : 0.0f;
  }
  __syncthreads();
  if (tid < 64) {
    float pred = (s.part[tid][0] + s.part[tid][1]) + s.part[tid][2];
    out[gqbase + tid] = pred;
  }
}

extern "C" void kernel_launch(void* const* d_in, const int* in_sizes, int n_in,
                              void* d_out, int out_size, void* d_ws, size_t ws_size,
                              hipStream_t stream) {
  const float* pts    = (const float*)d_in[0];
  const float* known2 = (const float*)d_in[1];
  const float* feats2 = (const float*)d_in[2];
  const float* known3 = (const float*)d_in[3];
  const float* feats3 = (const float*)d_in[4];
  const float* known4 = (const float*)d_in[5];
  const float* feats4 = (const float*)d_in[6];
  const float* match  = (const float*)d_in[7];
  const float* wfc    = (const float*)d_in[8];
  const float* wcls   = (const float*)d_in[9];

  char* ws = (char*)d_ws;
  CP* c0 = (CP*)(ws + OFF_C0);
  CP* c1 = (CP*)(ws + OFF_C1);
  CP* c2 = (CP*)(ws + OFF_C2);

  if (ws_size >= WS_NEW2) {
    CP* cmp = (CP*)(ws + OFF_CMP);
    u64* skey = (u64*)(ws + OFF_SKEY);
    float* boxes = (float*)(ws + OFF_BOX);
    float* wvg = (float*)(ws + OFF_WV);
    hipLaunchKernelGGL(prep_csort, dim3(5, NB), dim3(1024), 0, stream,
                       known2, known3, known4, match, pts, skey);
    hipLaunchKernelGGL(refine_emit, dim3(53, NB), dim3(512), 0, stream,
                       known2, known3, known4, match, pts, skey,
                       c0, c1, c2, cmp, boxes, wfc, wcls, wvg);
    hipLaunchKernelGGL(fused_sorted3, dim3(NQ / 32, NB), dim3(256), 0, stream,
                       pts, feats2, feats3, feats4, wvg,
                       c0, c1, c2, cmp, skey, boxes, (float*)d_out);
  } else if (ws_size >= WS_OLD) {
    DM* cm = (DM*)(ws + OFF_CM);
    hipLaunchKernelGGL(prep_kernel, dim3(64, 4), dim3(256), 0, stream,
                       known2, known3, known4, match, c0, c1, c2, cm);
    hipLaunchKernelGGL(HIP_KERNEL_NAME(fused_kernel<true>), dim3(NQ / 64, NB),
                       dim3(512), 0, stream, pts, known2, feats2, known3, feats3,
                       known4, feats4, match, wfc, wcls, c0, c1, c2, cm,
                       (float*)d_out);
  } else {
    DM* cm = (DM*)(ws + OFF_CM);
    hipLaunchKernelGGL(HIP_KERNEL_NAME(fused_kernel<false>), dim3(NQ / 64, NB),
                       dim3(512), 0, stream, pts, known2, feats2, known3, feats3,
                       known4, feats4, match, wfc, wcls, c0, c1, c2, cm,
                       (float*)d_out);
  }
}